// Round 1
// baseline (128.845 us; speedup 1.0000x reference)
//
#include <hip/hip_runtime.h>
#include <math.h>

// AttentionOptimizer: out = spins - LR*(grads + SMOOTH*g_smooth) + noise
// g_smooth via separable Gaussian-weighted softmax smoothing (see analysis).

namespace {

constexpr int LSIDE = 20;
constexpr int NVOX  = LSIDE * LSIDE * LSIDE;   // 8000
constexpr int NT    = 1024;
constexpr int KMAX  = (NVOX + NT - 1) / NT;    // 8

// One 1-D contraction along `axis` (0=x stride 400, 1=y stride 20, 2=z stride 1).
__device__ __forceinline__ void contract_axis(const float* __restrict__ src,
                                              float* __restrict__ dst,
                                              const float* __restrict__ kd,
                                              int axis, int tid) {
    for (int n = tid; n < NVOX; n += NT) {
        int idx, base, stride;
        if (axis == 0) {
            idx = n / 400; base = n - idx * 400; stride = 400;
        } else if (axis == 1) {
            int x = n / 400; int r = n - x * 400;
            idx = r / 20;  base = x * 400 + (r - idx * 20); stride = 20;
        } else {
            idx = n % 20;  base = n - idx; stride = 1;
        }
        float s = 0.0f;
        #pragma unroll
        for (int j = 0; j < LSIDE; ++j) {
            int d = idx > j ? idx - j : j - idx;
            s += kd[d] * src[base + j * stride];
        }
        dst[n] = s;
    }
}

__global__ __launch_bounds__(NT) void attn_opt_kernel(
    const float* __restrict__ grads,
    const float* __restrict__ spins,
    const float* __restrict__ noise,
    float* __restrict__ out)
{
    __shared__ float buf0[NVOX];   // 31.25 KB
    __shared__ float buf1[NVOX];   // 31.25 KB
    __shared__ float kd[LSIDE];

    const int b   = blockIdx.x;
    const int tid = threadIdx.x;
    const float* g  = grads + b * NVOX;
    const float* sp = spins + b * NVOX;
    const float* nz = noise + b * NVOX;
    float*       ob = out   + b * NVOX;

    // 1-D distance kernel: kd[d] = exp(-0.0125 * (d * 2/19)^2)
    if (tid < LSIDE) {
        float dx = (float)tid * (2.0f / 19.0f);
        kd[tid] = __expf(-0.0125f * dx * dx);
    }

    float den[KMAX], num[KMAX];

    // ================= field E = exp(-2*|g|) =================
    for (int n = tid; n < NVOX; n += NT)
        buf0[n] = __expf(-2.0f * fabsf(g[n]));
    __syncthreads();

    contract_axis(buf0, buf1, kd, 0, tid);   // x
    __syncthreads();
    contract_axis(buf1, buf0, kd, 1, tid);   // y
    __syncthreads();

    // z-contraction -> den registers (statically indexed)
    #pragma unroll
    for (int k = 0; k < KMAX; ++k) {
        int n = tid + k * NT;
        if (n < NVOX) {
            int zi = n % 20, base = n - zi;
            float s = 0.0f;
            #pragma unroll
            for (int j = 0; j < LSIDE; ++j) {
                int d = zi > j ? zi - j : j - zi;
                s += kd[d] * buf0[base + j];
            }
            den[k] = s;
        }
    }
    __syncthreads();   // all reads of buf0 done before reuse

    // ================= field W = g * exp(-2*|g|) =================
    for (int n = tid; n < NVOX; n += NT) {
        float gv = g[n];
        buf0[n] = gv * __expf(-2.0f * fabsf(gv));
    }
    __syncthreads();

    contract_axis(buf0, buf1, kd, 0, tid);   // x
    __syncthreads();
    contract_axis(buf1, buf0, kd, 1, tid);   // y
    __syncthreads();

    // z-contraction -> num registers + fused epilogue
    #pragma unroll
    for (int k = 0; k < KMAX; ++k) {
        int n = tid + k * NT;
        if (n < NVOX) {
            int zi = n % 20, base = n - zi;
            float s = 0.0f;
            #pragma unroll
            for (int j = 0; j < LSIDE; ++j) {
                int d = zi > j ? zi - j : j - zi;
                s += kd[d] * buf0[base + j];
            }
            num[k] = s;
        }
    }

    // epilogue: out = spins - LR*(grads + SMOOTH*num/den) + noise
    #pragma unroll
    for (int k = 0; k < KMAX; ++k) {
        int n = tid + k * NT;
        if (n < NVOX) {
            float gsm = num[k] / den[k];
            ob[n] = sp[n] - 0.05f * (g[n] + 10.0f * gsm) + nz[n];
        }
    }
}

} // namespace

extern "C" void kernel_launch(void* const* d_in, const int* in_sizes, int n_in,
                              void* d_out, int out_size, void* d_ws, size_t ws_size,
                              hipStream_t stream) {
    (void)in_sizes; (void)n_in; (void)d_ws; (void)ws_size; (void)out_size;
    const float* grads = (const float*)d_in[0];
    const float* spins = (const float*)d_in[1];
    // d_in[2] = pos: unused — grid positions are analytic (linspace(-1,1,20)^3),
    // and the 0.0125 exponent scale makes the ~1e-7 float difference irrelevant.
    const float* noise = (const float*)d_in[3];
    float* out = (float*)d_out;

    attn_opt_kernel<<<2, NT, 0, stream>>>(grads, spins, noise, out);
}

// Round 2
// 67.261 us; speedup vs baseline: 1.9156x; 1.9156x over previous
//
#include <hip/hip_runtime.h>
#include <math.h>

// AttentionOptimizer: out = spins - LR*(grads + SMOOTH*g_smooth) + noise
// g_smooth = (K * (g·e)) / (K * e),  e = exp(-2|g|),  K separable Gaussian
// (row-softmax max term cancels along the softmax axis; kernel separates
//  into kx·ky·kz on the regular grid).
//
// Two-kernel plan for parallelism (R1 was 2 blocks -> 0.3% occupancy):
//   K1: per (b,x) slice: e/w fields, z-contract, y-contract -> ws   [B*L blocks]
//   K2: per (b,x0):      x-contract + fused epilogue -> out         [B*L blocks]

namespace {

constexpr int LSIDE = 20;
constexpr int SLICE = LSIDE * LSIDE;           // 400
constexpr int NVOX  = LSIDE * SLICE;           // 8000

__device__ __forceinline__ float kdist(int d) {
    float dx = (float)d * (2.0f / 19.0f);
    return __expf(-0.0125f * dx * dx);
}

// ---------- K1: per (b,x) slice: e/w -> z-contract -> y-contract -> ws ----------
__global__ __launch_bounds__(256) void k1_slice(const float* __restrict__ grads,
                                                float* __restrict__ ws, int nb) {
    __shared__ float e[SLICE], w[SLICE], ez[SLICE], wz[SLICE];
    __shared__ float kd[LSIDE];

    const int b = blockIdx.x / LSIDE;
    const int x = blockIdx.x - b * LSIDE;
    const int t = threadIdx.x;
    if (t < LSIDE) kd[t] = kdist(t);

    const float* gs = grads + b * NVOX + x * SLICE;
    for (int o = t; o < SLICE; o += 256) {
        float gv = gs[o];
        float ev = __expf(-2.0f * fabsf(gv));
        e[o] = ev;
        w[o] = gv * ev;
    }
    __syncthreads();

    // z-contraction (per-lane same-row broadcast reads)
    for (int o = t; o < SLICE; o += 256) {
        int y = o / LSIDE, z0 = o - y * LSIDE;
        float se = 0.0f, sw = 0.0f;
        #pragma unroll
        for (int z = 0; z < LSIDE; ++z) {
            int d = z0 > z ? z0 - z : z - z0;
            float k = kd[d];
            se += k * e[y * LSIDE + z];
            sw += k * w[y * LSIDE + z];
        }
        ez[o] = se;
        wz[o] = sw;
    }
    __syncthreads();

    // y-contraction, write fields to workspace: EZY at ws[0..], WZY at ws[nb*NVOX..]
    float* EZY = ws;
    float* WZY = ws + (size_t)nb * NVOX;
    const int base = b * NVOX + x * SLICE;
    for (int o = t; o < SLICE; o += 256) {
        int y0 = o / LSIDE, z = o - y0 * LSIDE;
        float se = 0.0f, sw = 0.0f;
        #pragma unroll
        for (int y = 0; y < LSIDE; ++y) {
            int d = y0 > y ? y0 - y : y - y0;
            float k = kd[d];
            se += k * ez[y * LSIDE + z];
            sw += k * wz[y * LSIDE + z];
        }
        EZY[base + o] = se;
        WZY[base + o] = sw;
    }
}

// ---------- K2: per (b,x0): x-contract + fused epilogue ----------
__global__ __launch_bounds__(256) void k2_xmix(const float* __restrict__ grads,
                                               const float* __restrict__ spins,
                                               const float* __restrict__ noise,
                                               const float* __restrict__ ws,
                                               float* __restrict__ out, int nb) {
    __shared__ float kd[LSIDE];
    const int b  = blockIdx.x / LSIDE;
    const int x0 = blockIdx.x - b * LSIDE;
    const int t  = threadIdx.x;
    if (t < LSIDE) kd[t] = kdist(t);
    __syncthreads();

    const float* EZY = ws + (size_t)b * NVOX;
    const float* WZY = ws + (size_t)nb * NVOX + (size_t)b * NVOX;
    const int base = b * NVOX + x0 * SLICE;

    for (int o = t; o < SLICE; o += 256) {
        float den = 0.0f, num = 0.0f;
        #pragma unroll
        for (int x = 0; x < LSIDE; ++x) {
            int d = x0 > x ? x0 - x : x - x0;
            float k = kd[d];
            den += k * EZY[x * SLICE + o];   // coalesced across lanes
            num += k * WZY[x * SLICE + o];
        }
        float gsm = num / den;
        out[base + o] = spins[base + o]
                      - 0.05f * (grads[base + o] + 10.0f * gsm)
                      + noise[base + o];
    }
}

// ---------- fallback: R1 single-kernel path (used only if ws too small) ----------
constexpr int NT = 1024;
constexpr int KMAX = (NVOX + NT - 1) / NT;

__device__ __forceinline__ void contract_axis(const float* __restrict__ src,
                                              float* __restrict__ dst,
                                              const float* __restrict__ kd,
                                              int axis, int tid) {
    for (int n = tid; n < NVOX; n += NT) {
        int idx, base, stride;
        if (axis == 0)      { idx = n / 400; base = n - idx * 400; stride = 400; }
        else                { int x = n / 400; int r = n - x * 400;
                              idx = r / 20; base = x * 400 + (r - idx * 20); stride = 20; }
        float s = 0.0f;
        #pragma unroll
        for (int j = 0; j < LSIDE; ++j) {
            int d = idx > j ? idx - j : j - idx;
            s += kd[d] * src[base + j * stride];
        }
        dst[n] = s;
    }
}

__global__ __launch_bounds__(NT) void attn_opt_fallback(
    const float* __restrict__ grads, const float* __restrict__ spins,
    const float* __restrict__ noise, float* __restrict__ out) {
    __shared__ float buf0[NVOX], buf1[NVOX], kd[LSIDE];
    const int b = blockIdx.x, tid = threadIdx.x;
    const float* g = grads + b * NVOX; const float* sp = spins + b * NVOX;
    const float* nz = noise + b * NVOX; float* ob = out + b * NVOX;
    if (tid < LSIDE) kd[tid] = kdist(tid);
    float den[KMAX], num[KMAX];
    for (int n = tid; n < NVOX; n += NT) buf0[n] = __expf(-2.0f * fabsf(g[n]));
    __syncthreads();
    contract_axis(buf0, buf1, kd, 0, tid); __syncthreads();
    contract_axis(buf1, buf0, kd, 1, tid); __syncthreads();
    #pragma unroll
    for (int k = 0; k < KMAX; ++k) {
        int n = tid + k * NT;
        if (n < NVOX) {
            int zi = n % 20, base = n - zi; float s = 0.0f;
            #pragma unroll
            for (int j = 0; j < LSIDE; ++j) { int d = zi > j ? zi - j : j - zi; s += kd[d] * buf0[base + j]; }
            den[k] = s;
        }
    }
    __syncthreads();
    for (int n = tid; n < NVOX; n += NT) { float gv = g[n]; buf0[n] = gv * __expf(-2.0f * fabsf(gv)); }
    __syncthreads();
    contract_axis(buf0, buf1, kd, 0, tid); __syncthreads();
    contract_axis(buf1, buf0, kd, 1, tid); __syncthreads();
    #pragma unroll
    for (int k = 0; k < KMAX; ++k) {
        int n = tid + k * NT;
        if (n < NVOX) {
            int zi = n % 20, base = n - zi; float s = 0.0f;
            #pragma unroll
            for (int j = 0; j < LSIDE; ++j) { int d = zi > j ? zi - j : j - zi; s += kd[d] * buf0[base + j]; }
            num[k] = s;
        }
    }
    #pragma unroll
    for (int k = 0; k < KMAX; ++k) {
        int n = tid + k * NT;
        if (n < NVOX) ob[n] = sp[n] - 0.05f * (g[n] + 10.0f * (num[k] / den[k])) + nz[n];
    }
}

} // namespace

extern "C" void kernel_launch(void* const* d_in, const int* in_sizes, int n_in,
                              void* d_out, int out_size, void* d_ws, size_t ws_size,
                              hipStream_t stream) {
    (void)n_in; (void)out_size;
    const float* grads = (const float*)d_in[0];
    const float* spins = (const float*)d_in[1];
    // d_in[2] = pos: analytic regular grid, unused (see R0 analysis).
    const float* noise = (const float*)d_in[3];
    float* out = (float*)d_out;

    const int nb = in_sizes[0] / NVOX;                    // batch (=2)
    const size_t need = 2u * (size_t)nb * NVOX * sizeof(float);  // 128 KB

    if (ws_size >= need) {
        float* ws = (float*)d_ws;
        k1_slice<<<nb * LSIDE, 256, 0, stream>>>(grads, ws, nb);
        k2_xmix <<<nb * LSIDE, 256, 0, stream>>>(grads, spins, noise, ws, out, nb);
    } else {
        attn_opt_fallback<<<nb, NT, 0, stream>>>(grads, spins, noise, out);
    }
}

// Round 3
// 63.570 us; speedup vs baseline: 2.0268x; 1.0581x over previous
//
#include <hip/hip_runtime.h>
#include <math.h>

// AttentionOptimizer: out = spins - LR*(grads + SMOOTH*g_smooth) + noise
// g_smooth = (K * (g·e)) / (K * e),  e = exp(-2|g|),  K separable Gaussian
// (softmax row-max term cancels; kernel separates into kx·ky·kz on the grid).
//
// K1: per (b,x) slice: e/w fields -> z-contract -> y-contract -> ws (float2)
// K2: per (b,x0): x-contract from ws + fused epilogue. Sync-free, LDS-free.
// 1 element/thread everywhere; (e,w) packed as float2.

namespace {

constexpr int LSIDE = 20;
constexpr int SLICE = LSIDE * LSIDE;   // 400
constexpr int NVOX  = LSIDE * SLICE;   // 8000
constexpr int NT    = 512;             // 400 active + barrier-only lanes

__device__ __forceinline__ float kdist(int d) {
    float dx = (float)d * (2.0f / 19.0f);
    return __expf(-0.0125f * dx * dx);
}

// ---------- K1: per (b,x) slice -> ws[(b*L + x)*SLICE + o] = (E_zy, W_zy) ----------
__global__ __launch_bounds__(NT) void k1_slice(const float* __restrict__ grads,
                                               float2* __restrict__ ws) {
    __shared__ float2 ew[SLICE];   // (e, w)
    __shared__ float2 zc[SLICE];   // z-contracted
    __shared__ float  kd[LSIDE];

    const int b = blockIdx.x / LSIDE;
    const int x = blockIdx.x - b * LSIDE;
    const int t = threadIdx.x;

    if (t < LSIDE) kd[t] = kdist(t);

    if (t < SLICE) {
        float gv = grads[b * NVOX + x * SLICE + t];
        float ev = __expf(-2.0f * fabsf(gv));
        ew[t] = make_float2(ev, gv * ev);
    }
    __syncthreads();

    if (t < SLICE) {
        const int y = t / LSIDE, z0 = t - y * LSIDE;
        float se = 0.0f, sw = 0.0f;
        #pragma unroll
        for (int z = 0; z < LSIDE; ++z) {
            int d = z0 > z ? z0 - z : z - z0;
            float k = kd[d];
            float2 v = ew[y * LSIDE + z];     // same-row broadcast / distinct-bank
            se += k * v.x; sw += k * v.y;
        }
        zc[t] = make_float2(se, sw);
    }
    __syncthreads();

    if (t < SLICE) {
        const int y0 = t / LSIDE, z = t - y0 * LSIDE;
        float se = 0.0f, sw = 0.0f;
        #pragma unroll
        for (int y = 0; y < LSIDE; ++y) {
            int d = y0 > y ? y0 - y : y - y0;
            float k = kd[d];
            float2 v = zc[y * LSIDE + z];     // 2-way worst case: free (m136)
            se += k * v.x; sw += k * v.y;
        }
        ws[(b * LSIDE + x) * SLICE + t] = make_float2(se, sw);
    }
}

// ---------- K2: per (b,x0): x-contract + fused epilogue (no LDS, no syncs) ----------
__global__ __launch_bounds__(NT) void k2_xmix(const float* __restrict__ grads,
                                              const float* __restrict__ spins,
                                              const float* __restrict__ noise,
                                              const float2* __restrict__ ws,
                                              float* __restrict__ out) {
    const int b  = blockIdx.x / LSIDE;
    const int x0 = blockIdx.x - b * LSIDE;
    const int t  = threadIdx.x;
    if (t >= SLICE) return;                   // no barriers in this kernel

    const float2* wsb = ws + (size_t)b * LSIDE * SLICE;
    const int n = b * NVOX + x0 * SLICE + t;

    // Issue all loads up front (independent -> one pipelined vmcnt drain).
    float2 v[LSIDE];
    #pragma unroll
    for (int x = 0; x < LSIDE; ++x) v[x] = wsb[x * SLICE + t];   // coalesced
    const float spv = spins[n], gvv = grads[n], nzv = noise[n];

    // kd is block-uniform: registers via unrolled static indexing.
    float den = 0.0f, num = 0.0f;
    #pragma unroll
    for (int x = 0; x < LSIDE; ++x) {
        int d = x0 > x ? x0 - x : x - x0;
        float k = kdist(d);
        den += k * v[x].x; num += k * v[x].y;
    }

    out[n] = spv - 0.05f * (gvv + 10.0f * (num / den)) + nzv;
}

// ---------- fallback (only if ws too small; known-correct R1 path) ----------
constexpr int FNT = 1024;
constexpr int KMAX = (NVOX + FNT - 1) / FNT;

__device__ __forceinline__ void contract_axis(const float* __restrict__ src,
                                              float* __restrict__ dst,
                                              const float* __restrict__ kd,
                                              int axis, int tid) {
    for (int n = tid; n < NVOX; n += FNT) {
        int idx, base, stride;
        if (axis == 0)      { idx = n / 400; base = n - idx * 400; stride = 400; }
        else                { int x = n / 400; int r = n - x * 400;
                              idx = r / 20; base = x * 400 + (r - idx * 20); stride = 20; }
        float s = 0.0f;
        #pragma unroll
        for (int j = 0; j < LSIDE; ++j) {
            int d = idx > j ? idx - j : j - idx;
            s += kd[d] * src[base + j * stride];
        }
        dst[n] = s;
    }
}

__global__ __launch_bounds__(FNT) void attn_opt_fallback(
    const float* __restrict__ grads, const float* __restrict__ spins,
    const float* __restrict__ noise, float* __restrict__ out) {
    __shared__ float buf0[NVOX], buf1[NVOX], kd[LSIDE];
    const int b = blockIdx.x, tid = threadIdx.x;
    const float* g = grads + b * NVOX; const float* sp = spins + b * NVOX;
    const float* nz = noise + b * NVOX; float* ob = out + b * NVOX;
    if (tid < LSIDE) kd[tid] = kdist(tid);
    float den[KMAX], num[KMAX];
    for (int n = tid; n < NVOX; n += FNT) buf0[n] = __expf(-2.0f * fabsf(g[n]));
    __syncthreads();
    contract_axis(buf0, buf1, kd, 0, tid); __syncthreads();
    contract_axis(buf1, buf0, kd, 1, tid); __syncthreads();
    #pragma unroll
    for (int k = 0; k < KMAX; ++k) {
        int n = tid + k * FNT;
        if (n < NVOX) {
            int zi = n % 20, base = n - zi; float s = 0.0f;
            #pragma unroll
            for (int j = 0; j < LSIDE; ++j) { int d = zi > j ? zi - j : j - zi; s += kd[d] * buf0[base + j]; }
            den[k] = s;
        }
    }
    __syncthreads();
    for (int n = tid; n < NVOX; n += FNT) { float gv = g[n]; buf0[n] = gv * __expf(-2.0f * fabsf(gv)); }
    __syncthreads();
    contract_axis(buf0, buf1, kd, 0, tid); __syncthreads();
    contract_axis(buf1, buf0, kd, 1, tid); __syncthreads();
    #pragma unroll
    for (int k = 0; k < KMAX; ++k) {
        int n = tid + k * FNT;
        if (n < NVOX) {
            int zi = n % 20, base = n - zi; float s = 0.0f;
            #pragma unroll
            for (int j = 0; j < LSIDE; ++j) { int d = zi > j ? zi - j : j - zi; s += kd[d] * buf0[base + j]; }
            num[k] = s;
        }
    }
    #pragma unroll
    for (int k = 0; k < KMAX; ++k) {
        int n = tid + k * FNT;
        if (n < NVOX) ob[n] = sp[n] - 0.05f * (g[n] + 10.0f * (num[k] / den[k])) + nz[n];
    }
}

} // namespace

extern "C" void kernel_launch(void* const* d_in, const int* in_sizes, int n_in,
                              void* d_out, int out_size, void* d_ws, size_t ws_size,
                              hipStream_t stream) {
    (void)n_in; (void)out_size;
    const float* grads = (const float*)d_in[0];
    const float* spins = (const float*)d_in[1];
    // d_in[2] = pos: analytic regular grid, unused (see R0 analysis).
    const float* noise = (const float*)d_in[3];
    float* out = (float*)d_out;

    const int nb = in_sizes[0] / NVOX;                            // batch (=2)
    const size_t need = (size_t)nb * LSIDE * SLICE * sizeof(float2);  // 128 KB

    if (ws_size >= need) {
        float2* ws = (float2*)d_ws;
        k1_slice<<<nb * LSIDE, NT, 0, stream>>>(grads, ws);
        k2_xmix <<<nb * LSIDE, NT, 0, stream>>>(grads, spins, noise, ws, out);
    } else {
        attn_opt_fallback<<<nb, FNT, 0, stream>>>(grads, spins, noise, out);
    }
}